// Round 16
// baseline (245.618 us; speedup 1.0000x reference)
//
#include <hip/hip_runtime.h>
#include <math.h>

#define BNTOT 8192      // B*N
#define CH    64        // channels
#define KP1   11        // K+1 neighbors
#define NLOC  1568      // B * E  (8 * 196)
#define CAP   256       // per-row global candidate capacity (uint2 entries)
#define LCAP  32        // per-row per-block LDS candidate capacity
#define MARGIN 1.0f     // bf16 score-error margin for the filter (>= ~0.4 tail err)
#define DELTA  2.0f     // rescore cutoff slack

typedef __attribute__((ext_vector_type(8))) short short8;   // 8 bf16 (4 VGPRs)
typedef __attribute__((ext_vector_type(4))) float float4v;  // MFMA C/D

// ---------- helpers ----------
__device__ __forceinline__ int pcnt(int p) {
  int lo = p - 4; if (lo < 0) lo = 0; lo += (lo & 1);
  int hi = p; if (hi > 26) hi = 26;
  return (hi >= lo) ? (((hi - lo) >> 1) + 1) : 0;
}
__device__ __forceinline__ float dv2_of(int u) {
  int node = u & 1023;
  int rr = node >> 5, cc = node & 31;
  int dv = KP1 + pcnt(rr) * pcnt(cc);
  return 1.0f / sqrtf((float)dv);
}
__device__ __forceinline__ unsigned short f2bf(float f) {   // RNE fp32->bf16
  unsigned u = __float_as_uint(f);
  unsigned r = (u + 0x7FFFu + ((u >> 16) & 1u)) >> 16;
  return (unsigned short)r;
}
// monotone key: flip fp32 bits so unsigned compare == float compare
__device__ __forceinline__ unsigned long long skey(float s, int idx) {
  unsigned u = __float_as_uint(s);
  u = (u & 0x80000000u) ? ~u : (u | 0x80000000u);
  return ((unsigned long long)u << 32) | (unsigned)idx;
}

// ---------- K0: cast to bf16 + row squared norms (fused) ----------
__global__ void k_cast(const float* __restrict__ X, unsigned short* __restrict__ Xh,
                       float* __restrict__ sq) {
  int g = blockIdx.x * 256 + threadIdx.x;
  int lane = threadIdx.x & 63;
  float v = X[g];
  Xh[g] = f2bf(v);
  float s = v * v;
  #pragma unroll
  for (int off = 32; off >= 1; off >>= 1) s += __shfl_xor(s, off, 64);
  if (lane == 0) sq[g >> 6] = s;
}

// ---------- KA1: partial per-row top-11 over a 128-sample chunk ----------
// grid 1024 = 128 row-groups x 8 chunks; block 256 = 4 waves.
__global__ __launch_bounds__(256)
void k_thrpart(const float* __restrict__ X, const float* __restrict__ sq,
               float* __restrict__ part) {
  const int tid = threadIdx.x, wave = tid >> 6, lane = tid & 63;
  const int rg = blockIdx.x >> 3, chunk = blockIdx.x & 7;
  const int row = rg * 64 + lane;
  float xr[CH];
  {
    const float4* xp = (const float4*)(X + (size_t)row * CH);
    #pragma unroll
    for (int k = 0; k < CH / 4; ++k) {
      float4 v = xp[k];
      xr[4*k+0] = v.x; xr[4*k+1] = v.y; xr[4*k+2] = v.z; xr[4*k+3] = v.w;
    }
  }
  float tv[KP1];
  #pragma unroll
  for (int t = 0; t < KP1; ++t) tv[t] = INFINITY;

  for (int s = 0; s < 32; ++s) {
    int j = __builtin_amdgcn_readfirstlane(((chunk * 4 + wave) * 32 + s) * 8);
    const float* cp = X + (size_t)j * CH;
    float d0 = 0.f, d1 = 0.f, d2 = 0.f, d3 = 0.f;
    #pragma unroll
    for (int k = 0; k < CH / 4; ++k) {
      d0 = fmaf(xr[4*k+0], cp[4*k+0], d0);
      d1 = fmaf(xr[4*k+1], cp[4*k+1], d1);
      d2 = fmaf(xr[4*k+2], cp[4*k+2], d2);
      d3 = fmaf(xr[4*k+3], cp[4*k+3], d3);
    }
    float cv = fmaf(-2.0f, (d0 + d1) + (d2 + d3), sq[j]);
    #pragma unroll
    for (int t = 0; t < KP1; ++t) {
      float lo = fminf(tv[t], cv), hi = fmaxf(tv[t], cv);
      tv[t] = lo; cv = hi;
    }
  }
  __shared__ float ls[4][64][KP1];
  #pragma unroll
  for (int t = 0; t < KP1; ++t) ls[wave][lane][t] = tv[t];
  __syncthreads();
  if (tid < 64) {
    float v[KP1];
    #pragma unroll
    for (int t = 0; t < KP1; ++t) v[t] = ls[0][tid][t];
    #pragma unroll
    for (int w = 1; w < 4; ++w)
      #pragma unroll
      for (int t = 0; t < KP1; ++t) {
        float cv = ls[w][tid][t];
        #pragma unroll
        for (int s2 = 0; s2 < KP1; ++s2) {
          float lo = fminf(v[s2], cv), hi = fmaxf(v[s2], cv);
          v[s2] = lo; cv = hi;
        }
      }
    size_t base = ((size_t)blockIdx.x * 64 + tid) * KP1;
    #pragma unroll
    for (int t = 0; t < KP1; ++t) part[base + t] = v[t];
  }
}

// ---------- KB: MFMA all-pairs scores + filter -> LDS compaction -> (col,score) ----------
// R9-exact body + inline 8-chunk threshold merge in the prologue (bit-identical
// thresholds to the old k_thrmerge). grid 4096 = 128 row-tiles x 32 col-tiles.
__global__ __launch_bounds__(256)
void k_filter(const unsigned short* __restrict__ Xh, const float* __restrict__ sq,
              const float* __restrict__ thrpart, int* __restrict__ cnt,
              uint2* __restrict__ cand) {
  __shared__ uint2 lcand[64][LCAP];
  __shared__ int lcnt[64];
  __shared__ int lbase[64];
  __shared__ float thrs[64];

  const int tid = threadIdx.x, wave = tid >> 6, lane = tid & 63;
  const int m = lane & 15, q = lane >> 4;
  const int rowbase = (blockIdx.x >> 5) * 64;
  const int colbase = (blockIdx.x & 31) * 256 + wave * 64;

  if (tid < 64) lcnt[tid] = 0;

  // inline threshold merge (old k_thrmerge, rg = blockIdx.x>>5, row-lane = tid)
  if (tid < 64) {
    const int rg = blockIdx.x >> 5;
    float v[KP1];
    {
      size_t b0 = ((size_t)(rg * 8) * 64 + tid) * KP1;
      #pragma unroll
      for (int t = 0; t < KP1; ++t) v[t] = thrpart[b0 + t];
    }
    for (int c = 1; c < 8; ++c) {
      size_t b = ((size_t)(rg * 8 + c) * 64 + tid) * KP1;
      #pragma unroll
      for (int t = 0; t < KP1; ++t) {
        float cv = thrpart[b + t];
        #pragma unroll
        for (int s2 = 0; s2 < KP1; ++s2) {
          float lo = fminf(v[s2], cv), hi = fmaxf(v[s2], cv);
          v[s2] = lo; cv = hi;
        }
      }
    }
    thrs[tid] = v[KP1 - 1] + MARGIN;
  }

  // A fragments: 4 row-subtiles x 2 k-chunks (32 VGPRs)
  short8 a[4][2];
  #pragma unroll
  for (int rt = 0; rt < 4; ++rt)
    #pragma unroll
    for (int kc = 0; kc < 2; ++kc)
      a[rt][kc] = *(const short8*)(Xh + (size_t)(rowbase + rt * 16 + m) * CH + kc * 32 + q * 8);

  // B tiles for all 4 sub-cols + col norms: one load burst
  short8 b0[4], b1[4];
  float sqv[4];
  #pragma unroll
  for (int sub = 0; sub < 4; ++sub) {
    const int coln = colbase + sub * 16 + m;
    const short8* bp = (const short8*)(Xh + (size_t)coln * CH + q * 8);
    b0[sub] = bp[0];
    b1[sub] = bp[4];               // +32 bf16
    sqv[sub] = sq[coln];
  }

  __syncthreads();

  float thrv[16];
  #pragma unroll
  for (int rt = 0; rt < 4; ++rt)
    #pragma unroll
    for (int r = 0; r < 4; ++r)
      thrv[rt * 4 + r] = thrs[rt * 16 + q * 4 + r];

  const float4v cz = {0.f, 0.f, 0.f, 0.f};
  #pragma unroll
  for (int sub = 0; sub < 4; ++sub) {
    const int coln = colbase + sub * 16 + m;
    #pragma unroll
    for (int rt = 0; rt < 4; ++rt) {
      float4v c = __builtin_amdgcn_mfma_f32_16x16x32_bf16(a[rt][0], b0[sub], cz, 0, 0, 0);
      c = __builtin_amdgcn_mfma_f32_16x16x32_bf16(a[rt][1], b1[sub], c, 0, 0, 0);
      #pragma unroll
      for (int r = 0; r < 4; ++r) {
        float score = fmaf(-2.0f, c[r], sqv[sub]);
        if (score < thrv[rt * 4 + r]) {
          int rl = rt * 16 + q * 4 + r;
          uint2 ent; ent.x = (unsigned)coln; ent.y = __float_as_uint(score);
          int s = atomicAdd(&lcnt[rl], 1);
          if (s < LCAP) {
            lcand[rl][s] = ent;
          } else {                                   // rare overflow: direct global
            int gs = atomicAdd(&cnt[rowbase + rl], 1);
            if (gs < CAP) cand[(size_t)(rowbase + rl) * CAP + gs] = ent;
          }
        }
      }
    }
  }

  __syncthreads();
  if (tid < 64) {
    int nl = lcnt[tid]; if (nl > LCAP) nl = LCAP;
    lbase[tid] = atomicAdd(&cnt[rowbase + tid], nl);
    lcnt[tid] = nl;
  }
  __syncthreads();
  if (tid < 64) {
    int nl = lcnt[tid], base = lbase[tid];
    uint2* dst = cand + (size_t)(rowbase + tid) * CAP;
    for (int s = 0; s < nl; ++s) {
      int g = base + s;
      if (g < CAP) dst[g] = lcand[tid][s];
    }
  }
}

// ---------- KC: rescore, one wave per row. Normal path: bf-score prefilter +
// exact survivors. Overflow path (cnt>CAP, truncated list): exact full scan of
// all 8192 columns — correctness never depends on the candidate list there.
__global__ __launch_bounds__(256)
void k_rescore(const float* __restrict__ X, const float* __restrict__ sq,
               const int* __restrict__ cnt, const uint2* __restrict__ cand,
               int* __restrict__ inds, int* __restrict__ DE) {
  const int tid = threadIdx.x, lane = tid & 63;
  const int row = __builtin_amdgcn_readfirstlane(blockIdx.x * 4 + (tid >> 6));

  // own row (wave-uniform address -> scalar loads)
  float xr[CH];
  {
    const float4* xp = (const float4*)(X + (size_t)row * CH);
    #pragma unroll
    for (int k = 0; k < CH / 4; ++k) {
      float4 v = xp[k];
      xr[4*k+0] = v.x; xr[4*k+1] = v.y; xr[4*k+2] = v.z; xr[4*k+3] = v.w;
    }
  }
  const int nraw = cnt[row];

  float tv[KP1]; int ti[KP1];
  #pragma unroll
  for (int t = 0; t < KP1; ++t) { tv[t] = INFINITY; ti[t] = -1; }

  if (nraw <= CAP) {
    const int n = nraw;
    const int slotcnt = (n + 63) >> 6;        // 0..4

    // Phase A: load my candidate slots (coalesced)
    float bsc[4]; int bcol[4];
    #pragma unroll
    for (int a = 0; a < 4; ++a) { bsc[a] = INFINITY; bcol[a] = -1; }
    for (int a = 0; a < slotcnt; ++a) {
      int s = a * 64 + lane;
      if (s < n) {
        uint2 e = cand[(size_t)row * CAP + s];
        bcol[a] = (int)e.x; bsc[a] = __uint_as_float(e.y);
      }
    }
    // per-lane min, then 11 fminf-butterfly extractions (self-pop) -> c11 bound
    float curf = bsc[0];
    #pragma unroll
    for (int a = 1; a < 4; ++a) curf = fminf(curf, bsc[a]);
    float c11 = INFINITY;
    #pragma unroll
    for (int t = 0; t < KP1; ++t) {
      float mw = curf;
      #pragma unroll
      for (int off = 1; off < 64; off <<= 1) mw = fminf(mw, __shfl_xor(mw, off, 64));
      if (t == KP1 - 1) c11 = mw;
      if (curf == mw) curf = INFINITY;      // ties pop together: bound only loosens
    }
    const float cutoff = c11 + DELTA;

    // Phase B: exact gather-dot for survivors; insert into exact sorted-11
    for (int a = 0; a < slotcnt; ++a) {
      if (bsc[a] <= cutoff) {
        int cj = bcol[a];
        const float4* cp = (const float4*)(X + (size_t)cj * CH);
        float d0 = 0.f, d1 = 0.f, d2 = 0.f, d3 = 0.f;
        #pragma unroll
        for (int k = 0; k < CH / 4; ++k) {
          float4 v = cp[k];
          d0 = fmaf(xr[4*k+0], v.x, d0);
          d1 = fmaf(xr[4*k+1], v.y, d1);
          d2 = fmaf(xr[4*k+2], v.z, d2);
          d3 = fmaf(xr[4*k+3], v.w, d3);
        }
        float score = fmaf(-2.0f, (d0 + d1) + (d2 + d3), sq[cj]);
        if (score < tv[KP1 - 1]) {
          float cv = score; int ci = cj;
          #pragma unroll
          for (int t = 0; t < KP1; ++t) {
            bool sw = cv < tv[t];
            float nv = sw ? cv   : tv[t]; int ni = sw ? ci   : ti[t];
            float ov = sw ? tv[t] : cv;   int oi = sw ? ti[t] : ci;
            tv[t] = nv; ti[t] = ni; cv = ov; ci = oi;
          }
        }
      }
    }
  } else {
    // Fallback: candidate list truncated -> exact full scan (round-5-proven loop)
    for (int s = lane; s < BNTOT; s += 64) {
      const float4* cp = (const float4*)(X + (size_t)s * CH);
      float d0 = 0.f, d1 = 0.f, d2 = 0.f, d3 = 0.f;
      #pragma unroll
      for (int k = 0; k < CH / 4; ++k) {
        float4 v = cp[k];
        d0 = fmaf(xr[4*k+0], v.x, d0);
        d1 = fmaf(xr[4*k+1], v.y, d1);
        d2 = fmaf(xr[4*k+2], v.z, d2);
        d3 = fmaf(xr[4*k+3], v.w, d3);
      }
      float score = fmaf(-2.0f, (d0 + d1) + (d2 + d3), sq[s]);
      if (score < tv[KP1 - 1]) {
        float cv = score; int ci = s;
        #pragma unroll
        for (int t = 0; t < KP1; ++t) {
          bool sw = cv < tv[t];
          float nv = sw ? cv   : tv[t]; int ni = sw ? ci   : ti[t];
          float ov = sw ? tv[t] : cv;   int oi = sw ? ti[t] : ci;
          tv[t] = nv; ti[t] = ni; cv = ov; ci = oi;
        }
      }
    }
  }

  // Phase C: 11 wave-min extractions on u64 keys (round-6 proven)
  unsigned long long cur = skey(tv[0], ti[0]);
  unsigned long long keep = 0;
  #pragma unroll
  for (int t = 0; t < KP1; ++t) {
    unsigned long long mw = cur;
    #pragma unroll
    for (int off = 1; off < 64; off <<= 1) {
      unsigned lo = __shfl_xor((unsigned)mw, off, 64);
      unsigned hi = __shfl_xor((unsigned)(mw >> 32), off, 64);
      unsigned long long o = ((unsigned long long)hi << 32) | lo;
      mw = (o < mw) ? o : mw;
    }
    if (lane == t) keep = mw;
    if (cur == mw) {                      // winner pops its front
      #pragma unroll
      for (int q = 0; q < KP1 - 1; ++q) { tv[q] = tv[q+1]; ti[q] = ti[q+1]; }
      tv[KP1-1] = INFINITY; ti[KP1-1] = -1;
      cur = skey(tv[0], ti[0]);
    }
  }
  if (lane < KP1) {
    int idx = (int)(unsigned)(keep & 0xFFFFFFFFull);
    inds[(size_t)row * KP1 + lane] = idx;
    atomicAdd(&DE[idx], 1);
  }
}

// ---------- K3: t = Dv^{-1/2} * (x @ W^T + b) ----------
// grid 512: 4 waves/block x 4 rows/wave.
__global__ void k_lin(const float* __restrict__ X, const float* __restrict__ W,
                      const float* __restrict__ bias, float* __restrict__ t) {
  int lane = threadIdx.x & 63;
  int wave = threadIdx.x >> 6;
  int rowbase = (blockIdx.x * 4 + wave) * 4;
  float wr[CH];
  {
    const float4* wp = (const float4*)(W + (size_t)lane * CH);
    #pragma unroll
    for (int k = 0; k < CH / 4; ++k) {
      float4 v = wp[k];
      wr[4*k+0] = v.x; wr[4*k+1] = v.y; wr[4*k+2] = v.z; wr[4*k+3] = v.w;
    }
  }
  float bc = bias[lane];
  #pragma unroll
  for (int r = 0; r < 4; ++r) {
    int row = __builtin_amdgcn_readfirstlane(rowbase + r);
    const float* xp = X + (size_t)row * CH;
    float d0 = 0.f, d1 = 0.f, d2 = 0.f, d3 = 0.f;
    #pragma unroll
    for (int k = 0; k < CH / 4; ++k) {
      d0 = fmaf(wr[4*k+0], xp[4*k+0], d0);
      d1 = fmaf(wr[4*k+1], xp[4*k+1], d1);
      d2 = fmaf(wr[4*k+2], xp[4*k+2], d2);
      d3 = fmaf(wr[4*k+3], xp[4*k+3], d3);
    }
    float y = (d0 + d1) + (d2 + d3) + bc;
    t[(size_t)row * CH + lane] = y * dv2_of(row);
  }
}

// ---------- K4: fused edge sums — scatter (KNN, atomics) + local patches ----------
// grid 2048+392: first 2048 blocks = scatter (4 nodes each), rest = local (4 edges each).
__global__ void k_edge(const float* __restrict__ t, const int* __restrict__ inds,
                       float* __restrict__ s_knn, float* __restrict__ s_loc) {
  int c = threadIdx.x & 63;
  int w = threadIdx.x >> 6;
  if (blockIdx.x < BNTOT / 4) {
    int u = blockIdx.x * 4 + w;
    float val = t[(size_t)u * CH + c];
    int ub = __builtin_amdgcn_readfirstlane(u);
    const int* ip = inds + (size_t)ub * KP1;
    #pragma unroll
    for (int j = 0; j < KP1; ++j) {
      int e = ip[j];
      atomicAdd(&s_knn[(size_t)e * CH + c], val);
    }
  } else {
    int e = (blockIdx.x - BNTOT / 4) * 4 + w;
    int b  = e / 196;
    int le = e - b * 196;
    int pi = le / 14;
    int pj = le - pi * 14;
    int base = b * 1024 + (pi * 2) * 32 + pj * 2;
    float acc = 0.f;
    #pragma unroll
    for (int di = 0; di < 5; ++di)
      #pragma unroll
      for (int dj = 0; dj < 5; ++dj)
        acc += t[(size_t)(base + di * 32 + dj) * CH + c];
    s_loc[(size_t)e * CH + c] = acc * (1.0f / 25.0f);
  }
}

// ---------- K5: gather + per-block BN partials (R14-proven gather body) ----------
__global__ void k_gatherbn(const float* __restrict__ s_knn, const float* __restrict__ s_loc,
                           const int* __restrict__ inds, const int* __restrict__ DE,
                           float* __restrict__ z, float* __restrict__ part,
                           float* __restrict__ partsq) {
  int c = threadIdx.x & 63;
  int w = threadIdx.x >> 6;
  int u = blockIdx.x * 4 + w;
  int ub = __builtin_amdgcn_readfirstlane(u);
  const int* ip = inds + (size_t)ub * KP1;
  float acc = 0.f;
  #pragma unroll
  for (int j = 0; j < KP1; ++j) {
    int e = ip[j];
    float invde = 1.0f / (float)DE[e];
    acc += s_knn[(size_t)e * CH + c] * invde;
  }
  int node = ub & 1023, b = ub >> 10;
  int rr = node >> 5, cc = node & 31;
  int i0 = rr - 4; if (i0 < 0) i0 = 0; i0 += (i0 & 1);
  int i1 = rr; if (i1 > 26) i1 = 26;
  int j0 = cc - 4; if (j0 < 0) j0 = 0; j0 += (j0 & 1);
  int j1 = cc; if (j1 > 26) j1 = 26;
  for (int i = i0; i <= i1; i += 2)
    for (int jj = j0; jj <= j1; jj += 2) {
      int e = b * 196 + (i >> 1) * 14 + (jj >> 1);
      acc += s_loc[(size_t)e * CH + c];
    }
  float zv = acc * dv2_of(ub);
  z[(size_t)ub * CH + c] = zv;

  __shared__ float ls[4][CH], ls2[4][CH];
  ls[w][c] = zv; ls2[w][c] = zv * zv;
  __syncthreads();
  if (threadIdx.x < 64) {
    part[(size_t)blockIdx.x * CH + c]   = ls[0][c] + ls[1][c] + ls[2][c] + ls[3][c];
    partsq[(size_t)blockIdx.x * CH + c] = ls2[0][c] + ls2[1][c] + ls2[2][c] + ls2[3][c];
  }
}

// ---------- K6: parallel reduce 2048 partials -> 32 (k_bnpart-shaped) ----------
__global__ void k_bnfin1(const float* __restrict__ part, const float* __restrict__ partsq,
                         float* __restrict__ part2, float* __restrict__ partsq2) {
  int c = threadIdx.x & 63;
  int rq = threadIdx.x >> 6;
  int blk = blockIdx.x;
  float s = 0.f, s2 = 0.f;
  for (int k = 0; k < 16; ++k) {
    size_t r = (size_t)(blk * 64 + rq * 16 + k) * CH + c;
    s += part[r]; s2 += partsq[r];
  }
  __shared__ float ls[4][CH], ls2[4][CH];
  ls[rq][c] = s; ls2[rq][c] = s2;
  __syncthreads();
  if (rq == 0) {
    part2[(size_t)blk * CH + c]   = ls[0][c] + ls[1][c] + ls[2][c] + ls[3][c];
    partsq2[(size_t)blk * CH + c] = ls2[0][c] + ls2[1][c] + ls2[2][c] + ls2[3][c];
  }
}

// ---------- K7: BN finalize (32 partials) + apply + relu + residual ----------
__global__ void k_out(const float* __restrict__ z, const float* __restrict__ X,
                      const float* __restrict__ part2, const float* __restrict__ partsq2,
                      const float* __restrict__ gamma, const float* __restrict__ beta,
                      float* __restrict__ out) {
  __shared__ float ls[4][CH], ls2[4][CH], smu[CH], srstd[CH];
  int c = threadIdx.x & 63;
  int w = threadIdx.x >> 6;
  // prologue: reduce the 32 level-2 partials (8 per wave)
  float s = 0.f, s2 = 0.f;
  #pragma unroll
  for (int b = 0; b < 8; ++b) {
    size_t r = (size_t)(w * 8 + b) * CH + c;
    s += part2[r]; s2 += partsq2[r];
  }
  ls[w][c] = s; ls2[w][c] = s2;
  __syncthreads();
  if (threadIdx.x < 64) {
    float S  = ls[0][c] + ls[1][c] + ls[2][c] + ls[3][c];
    float S2 = ls2[0][c] + ls2[1][c] + ls2[2][c] + ls2[3][c];
    float m = S * (1.0f / (float)BNTOT);
    float var = S2 * (1.0f / (float)BNTOT) - m * m;
    smu[c] = m;
    srstd[c] = 1.0f / sqrtf(var + 1e-5f);
  }
  __syncthreads();

  int u = blockIdx.x * 4 + w;
  size_t idx = (size_t)u * CH + c;
  float zn = (z[idx] - smu[c]) * srstd[c] * gamma[c] + beta[c];
  out[idx] = fmaxf(zn, 0.f) + X[idx];
}

// ---------- launch ----------
extern "C" void kernel_launch(void* const* d_in, const int* in_sizes, int n_in,
                              void* d_out, int out_size, void* d_ws, size_t ws_size,
                              hipStream_t stream) {
  const float* X     = (const float*)d_in[0];
  const float* W     = (const float*)d_in[1];
  const float* bias  = (const float*)d_in[2];
  const float* gamma = (const float*)d_in[3];
  const float* beta  = (const float*)d_in[4];
  float* out = (float*)d_out;

  // workspace layout
  float* ws = (float*)d_ws;
  float* sq      = ws;                        // 8192
  float* t       = sq + 8192;                 // 524288
  float* s_loc   = t + 524288;                // 100352
  float* z       = s_loc + 100352;            // 524288
  float* part    = z + 524288;                // 2048*64 = 131072
  float* partsq  = part + 131072;             // 131072
  float* part2   = partsq + 131072;           // 32*64 = 2048
  float* partsq2 = part2 + 2048;              // 2048
  float* thrpart = partsq2 + 2048;            // 1024*64*11 = 720896
  int*   inds    = (int*)(thrpart + 720896);  // 90112 ints
  unsigned short* Xh = (unsigned short*)(inds + 90112);   // 524288 shorts
  uint2* cand    = (uint2*)(Xh + 524288);                 // 8192*256 uint2 = 16 MB
  // zeroed region: cnt (8192 int) + DE (8192 int) + s_knn (524288 f), contiguous
  int*   cnt    = (int*)(cand + (size_t)8192 * CAP);
  int*   DE     = cnt + 8192;
  float* s_knn  = (float*)(DE + 8192);

  hipMemsetAsync(cnt, 0, (size_t)(8192 + 8192 + 524288) * 4, stream);

  k_cast    <<<2048, 256, 0, stream>>>(X, Xh, sq);
  k_thrpart <<<1024, 256, 0, stream>>>(X, sq, thrpart);
  k_filter  <<<4096, 256, 0, stream>>>(Xh, sq, thrpart, cnt, cand);
  k_rescore <<<2048, 256, 0, stream>>>(X, sq, cnt, cand, inds, DE);
  k_lin     <<<512, 256, 0, stream>>>(X, W, bias, t);
  k_edge    <<<BNTOT / 4 + NLOC / 4, 256, 0, stream>>>(t, inds, s_knn, s_loc);
  k_gatherbn<<<BNTOT / 4, 256, 0, stream>>>(s_knn, s_loc, inds, DE, z, part, partsq);
  k_bnfin1  <<<32, 256, 0, stream>>>(part, partsq, part2, partsq2);
  k_out     <<<BNTOT / 4, 256, 0, stream>>>(z, X, part2, partsq2, gamma, beta, out);

  (void)in_sizes; (void)n_in; (void)out_size; (void)ws_size;
}

// Round 17
// 231.823 us; speedup vs baseline: 1.0595x; 1.0595x over previous
//
#include <hip/hip_runtime.h>
#include <math.h>

#define BNTOT 8192      // B*N
#define CH    64        // channels
#define KP1   11        // K+1 neighbors
#define NLOC  1568      // B * E  (8 * 196)
#define CAP   256       // per-row global candidate capacity (uint2 entries)
#define LCAP  32        // per-row per-block LDS candidate capacity
#define MARGIN 1.0f     // bf16 score-error margin for the filter (>= ~0.4 tail err)
#define DELTA  2.0f     // rescore cutoff slack

typedef __attribute__((ext_vector_type(8))) short short8;   // 8 bf16 (4 VGPRs)
typedef __attribute__((ext_vector_type(4))) float float4v;  // MFMA C/D

// ---------- helpers ----------
__device__ __forceinline__ int pcnt(int p) {
  int lo = p - 4; if (lo < 0) lo = 0; lo += (lo & 1);
  int hi = p; if (hi > 26) hi = 26;
  return (hi >= lo) ? (((hi - lo) >> 1) + 1) : 0;
}
__device__ __forceinline__ float dv2_of(int u) {
  int node = u & 1023;
  int rr = node >> 5, cc = node & 31;
  int dv = KP1 + pcnt(rr) * pcnt(cc);
  return 1.0f / sqrtf((float)dv);
}
__device__ __forceinline__ unsigned short f2bf(float f) {   // RNE fp32->bf16
  unsigned u = __float_as_uint(f);
  unsigned r = (u + 0x7FFFu + ((u >> 16) & 1u)) >> 16;
  return (unsigned short)r;
}
// monotone key: flip fp32 bits so unsigned compare == float compare
__device__ __forceinline__ unsigned long long skey(float s, int idx) {
  unsigned u = __float_as_uint(s);
  u = (u & 0x80000000u) ? ~u : (u | 0x80000000u);
  return ((unsigned long long)u << 32) | (unsigned)idx;
}

// ---------- K0: cast to bf16 + row squared norms (fused) ----------
__global__ void k_cast(const float* __restrict__ X, unsigned short* __restrict__ Xh,
                       float* __restrict__ sq) {
  int g = blockIdx.x * 256 + threadIdx.x;
  int lane = threadIdx.x & 63;
  float v = X[g];
  Xh[g] = f2bf(v);
  float s = v * v;
  #pragma unroll
  for (int off = 32; off >= 1; off >>= 1) s += __shfl_xor(s, off, 64);
  if (lane == 0) sq[g >> 6] = s;
}

// ---------- KA1: partial per-row top-11 over a 128-sample chunk ----------
// grid 1024 = 128 row-groups x 8 chunks; block 256 = 4 waves.
__global__ __launch_bounds__(256)
void k_thrpart(const float* __restrict__ X, const float* __restrict__ sq,
               float* __restrict__ part) {
  const int tid = threadIdx.x, wave = tid >> 6, lane = tid & 63;
  const int rg = blockIdx.x >> 3, chunk = blockIdx.x & 7;
  const int row = rg * 64 + lane;
  float xr[CH];
  {
    const float4* xp = (const float4*)(X + (size_t)row * CH);
    #pragma unroll
    for (int k = 0; k < CH / 4; ++k) {
      float4 v = xp[k];
      xr[4*k+0] = v.x; xr[4*k+1] = v.y; xr[4*k+2] = v.z; xr[4*k+3] = v.w;
    }
  }
  float tv[KP1];
  #pragma unroll
  for (int t = 0; t < KP1; ++t) tv[t] = INFINITY;

  for (int s = 0; s < 32; ++s) {
    int j = __builtin_amdgcn_readfirstlane(((chunk * 4 + wave) * 32 + s) * 8);
    const float* cp = X + (size_t)j * CH;
    float d0 = 0.f, d1 = 0.f, d2 = 0.f, d3 = 0.f;
    #pragma unroll
    for (int k = 0; k < CH / 4; ++k) {
      d0 = fmaf(xr[4*k+0], cp[4*k+0], d0);
      d1 = fmaf(xr[4*k+1], cp[4*k+1], d1);
      d2 = fmaf(xr[4*k+2], cp[4*k+2], d2);
      d3 = fmaf(xr[4*k+3], cp[4*k+3], d3);
    }
    float cv = fmaf(-2.0f, (d0 + d1) + (d2 + d3), sq[j]);
    #pragma unroll
    for (int t = 0; t < KP1; ++t) {
      float lo = fminf(tv[t], cv), hi = fmaxf(tv[t], cv);
      tv[t] = lo; cv = hi;
    }
  }
  __shared__ float ls[4][64][KP1];
  #pragma unroll
  for (int t = 0; t < KP1; ++t) ls[wave][lane][t] = tv[t];
  __syncthreads();
  if (tid < 64) {
    float v[KP1];
    #pragma unroll
    for (int t = 0; t < KP1; ++t) v[t] = ls[0][tid][t];
    #pragma unroll
    for (int w = 1; w < 4; ++w)
      #pragma unroll
      for (int t = 0; t < KP1; ++t) {
        float cv = ls[w][tid][t];
        #pragma unroll
        for (int s2 = 0; s2 < KP1; ++s2) {
          float lo = fminf(v[s2], cv), hi = fmaxf(v[s2], cv);
          v[s2] = lo; cv = hi;
        }
      }
    size_t base = ((size_t)blockIdx.x * 64 + tid) * KP1;
    #pragma unroll
    for (int t = 0; t < KP1; ++t) part[base + t] = v[t];
  }
}

// ---------- KA2: merge 8 chunk-partials -> per-row threshold ----------
__global__ void k_thrmerge(const float* __restrict__ part, float* __restrict__ thr) {
  const int rg = blockIdx.x, lane = threadIdx.x;
  const int row = rg * 64 + lane;
  float v[KP1];
  {
    size_t b0 = ((size_t)(rg * 8) * 64 + lane) * KP1;
    #pragma unroll
    for (int t = 0; t < KP1; ++t) v[t] = part[b0 + t];
  }
  for (int c = 1; c < 8; ++c) {
    size_t b = ((size_t)(rg * 8 + c) * 64 + lane) * KP1;
    #pragma unroll
    for (int t = 0; t < KP1; ++t) {
      float cv = part[b + t];
      #pragma unroll
      for (int s2 = 0; s2 < KP1; ++s2) {
        float lo = fminf(v[s2], cv), hi = fmaxf(v[s2], cv);
        v[s2] = lo; cv = hi;
      }
    }
  }
  thr[row] = v[KP1 - 1] + MARGIN;
}

// ---------- KB: MFMA all-pairs scores + filter -> LDS compaction -> (col,score) ----------
// R9-exact config (empirically fastest of seven variants, 48.5us):
// grid 4096 = 128 row-tiles(64 rows) x 32 col-tiles(256 cols); block 256 = 4 waves.
__global__ __launch_bounds__(256)
void k_filter(const unsigned short* __restrict__ Xh, const float* __restrict__ sq,
              const float* __restrict__ thr, int* __restrict__ cnt,
              uint2* __restrict__ cand) {
  __shared__ uint2 lcand[64][LCAP];
  __shared__ int lcnt[64];
  __shared__ int lbase[64];

  const int tid = threadIdx.x, wave = tid >> 6, lane = tid & 63;
  const int m = lane & 15, q = lane >> 4;
  const int rowbase = (blockIdx.x >> 5) * 64;
  const int colbase = (blockIdx.x & 31) * 256 + wave * 64;

  if (tid < 64) lcnt[tid] = 0;

  // A fragments: 4 row-subtiles x 2 k-chunks (32 VGPRs)
  short8 a[4][2];
  #pragma unroll
  for (int rt = 0; rt < 4; ++rt)
    #pragma unroll
    for (int kc = 0; kc < 2; ++kc)
      a[rt][kc] = *(const short8*)(Xh + (size_t)(rowbase + rt * 16 + m) * CH + kc * 32 + q * 8);

  // B tiles for all 4 sub-cols + col norms: one load burst
  short8 b0[4], b1[4];
  float sqv[4];
  #pragma unroll
  for (int sub = 0; sub < 4; ++sub) {
    const int coln = colbase + sub * 16 + m;
    const short8* bp = (const short8*)(Xh + (size_t)coln * CH + q * 8);
    b0[sub] = bp[0];
    b1[sub] = bp[4];               // +32 bf16
    sqv[sub] = sq[coln];
  }

  float thrv[16];
  #pragma unroll
  for (int rt = 0; rt < 4; ++rt)
    #pragma unroll
    for (int r = 0; r < 4; ++r)
      thrv[rt * 4 + r] = thr[rowbase + rt * 16 + q * 4 + r];

  __syncthreads();

  const float4v cz = {0.f, 0.f, 0.f, 0.f};
  #pragma unroll
  for (int sub = 0; sub < 4; ++sub) {
    const int coln = colbase + sub * 16 + m;
    #pragma unroll
    for (int rt = 0; rt < 4; ++rt) {
      float4v c = __builtin_amdgcn_mfma_f32_16x16x32_bf16(a[rt][0], b0[sub], cz, 0, 0, 0);
      c = __builtin_amdgcn_mfma_f32_16x16x32_bf16(a[rt][1], b1[sub], c, 0, 0, 0);
      #pragma unroll
      for (int r = 0; r < 4; ++r) {
        float score = fmaf(-2.0f, c[r], sqv[sub]);
        if (score < thrv[rt * 4 + r]) {
          int rl = rt * 16 + q * 4 + r;
          uint2 ent; ent.x = (unsigned)coln; ent.y = __float_as_uint(score);
          int s = atomicAdd(&lcnt[rl], 1);
          if (s < LCAP) {
            lcand[rl][s] = ent;
          } else {                                   // rare overflow: direct global
            int gs = atomicAdd(&cnt[rowbase + rl], 1);
            if (gs < CAP) cand[(size_t)(rowbase + rl) * CAP + gs] = ent;
          }
        }
      }
    }
  }

  __syncthreads();
  if (tid < 64) {
    int nl = lcnt[tid]; if (nl > LCAP) nl = LCAP;
    lbase[tid] = atomicAdd(&cnt[rowbase + tid], nl);
    lcnt[tid] = nl;
  }
  __syncthreads();
  if (tid < 64) {
    int nl = lcnt[tid], base = lbase[tid];
    uint2* dst = cand + (size_t)(rowbase + tid) * CAP;
    for (int s = 0; s < nl; ++s) {
      int g = base + s;
      if (g < CAP) dst[g] = lcand[tid][s];
    }
  }
}

// ---------- KC: rescore, one wave per row. Normal path: bf-score prefilter +
// exact survivors. Overflow path (cnt>CAP, truncated list): exact full scan of
// all 8192 columns — correctness never depends on the candidate list there.
__global__ __launch_bounds__(256)
void k_rescore(const float* __restrict__ X, const float* __restrict__ sq,
               const int* __restrict__ cnt, const uint2* __restrict__ cand,
               int* __restrict__ inds, int* __restrict__ DE) {
  const int tid = threadIdx.x, lane = tid & 63;
  const int row = __builtin_amdgcn_readfirstlane(blockIdx.x * 4 + (tid >> 6));

  // own row (wave-uniform address -> scalar loads)
  float xr[CH];
  {
    const float4* xp = (const float4*)(X + (size_t)row * CH);
    #pragma unroll
    for (int k = 0; k < CH / 4; ++k) {
      float4 v = xp[k];
      xr[4*k+0] = v.x; xr[4*k+1] = v.y; xr[4*k+2] = v.z; xr[4*k+3] = v.w;
    }
  }
  const int nraw = cnt[row];

  float tv[KP1]; int ti[KP1];
  #pragma unroll
  for (int t = 0; t < KP1; ++t) { tv[t] = INFINITY; ti[t] = -1; }

  if (nraw <= CAP) {
    const int n = nraw;
    const int slotcnt = (n + 63) >> 6;        // 0..4

    // Phase A: load my candidate slots (coalesced)
    float bsc[4]; int bcol[4];
    #pragma unroll
    for (int a = 0; a < 4; ++a) { bsc[a] = INFINITY; bcol[a] = -1; }
    for (int a = 0; a < slotcnt; ++a) {
      int s = a * 64 + lane;
      if (s < n) {
        uint2 e = cand[(size_t)row * CAP + s];
        bcol[a] = (int)e.x; bsc[a] = __uint_as_float(e.y);
      }
    }
    // per-lane min, then 11 fminf-butterfly extractions (self-pop) -> c11 bound
    float curf = bsc[0];
    #pragma unroll
    for (int a = 1; a < 4; ++a) curf = fminf(curf, bsc[a]);
    float c11 = INFINITY;
    #pragma unroll
    for (int t = 0; t < KP1; ++t) {
      float mw = curf;
      #pragma unroll
      for (int off = 1; off < 64; off <<= 1) mw = fminf(mw, __shfl_xor(mw, off, 64));
      if (t == KP1 - 1) c11 = mw;
      if (curf == mw) curf = INFINITY;      // ties pop together: bound only loosens
    }
    const float cutoff = c11 + DELTA;

    // Phase B: exact gather-dot for survivors; insert into exact sorted-11
    for (int a = 0; a < slotcnt; ++a) {
      if (bsc[a] <= cutoff) {
        int cj = bcol[a];
        const float4* cp = (const float4*)(X + (size_t)cj * CH);
        float d0 = 0.f, d1 = 0.f, d2 = 0.f, d3 = 0.f;
        #pragma unroll
        for (int k = 0; k < CH / 4; ++k) {
          float4 v = cp[k];
          d0 = fmaf(xr[4*k+0], v.x, d0);
          d1 = fmaf(xr[4*k+1], v.y, d1);
          d2 = fmaf(xr[4*k+2], v.z, d2);
          d3 = fmaf(xr[4*k+3], v.w, d3);
        }
        float score = fmaf(-2.0f, (d0 + d1) + (d2 + d3), sq[cj]);
        if (score < tv[KP1 - 1]) {
          float cv = score; int ci = cj;
          #pragma unroll
          for (int t = 0; t < KP1; ++t) {
            bool sw = cv < tv[t];
            float nv = sw ? cv   : tv[t]; int ni = sw ? ci   : ti[t];
            float ov = sw ? tv[t] : cv;   int oi = sw ? ti[t] : ci;
            tv[t] = nv; ti[t] = ni; cv = ov; ci = oi;
          }
        }
      }
    }
  } else {
    // Fallback: candidate list truncated -> exact full scan (round-5-proven loop)
    for (int s = lane; s < BNTOT; s += 64) {
      const float4* cp = (const float4*)(X + (size_t)s * CH);
      float d0 = 0.f, d1 = 0.f, d2 = 0.f, d3 = 0.f;
      #pragma unroll
      for (int k = 0; k < CH / 4; ++k) {
        float4 v = cp[k];
        d0 = fmaf(xr[4*k+0], v.x, d0);
        d1 = fmaf(xr[4*k+1], v.y, d1);
        d2 = fmaf(xr[4*k+2], v.z, d2);
        d3 = fmaf(xr[4*k+3], v.w, d3);
      }
      float score = fmaf(-2.0f, (d0 + d1) + (d2 + d3), sq[s]);
      if (score < tv[KP1 - 1]) {
        float cv = score; int ci = s;
        #pragma unroll
        for (int t = 0; t < KP1; ++t) {
          bool sw = cv < tv[t];
          float nv = sw ? cv   : tv[t]; int ni = sw ? ci   : ti[t];
          float ov = sw ? tv[t] : cv;   int oi = sw ? ti[t] : ci;
          tv[t] = nv; ti[t] = ni; cv = ov; ci = oi;
        }
      }
    }
  }

  // Phase C: 11 wave-min extractions on u64 keys (round-6 proven)
  unsigned long long cur = skey(tv[0], ti[0]);
  unsigned long long keep = 0;
  #pragma unroll
  for (int t = 0; t < KP1; ++t) {
    unsigned long long mw = cur;
    #pragma unroll
    for (int off = 1; off < 64; off <<= 1) {
      unsigned lo = __shfl_xor((unsigned)mw, off, 64);
      unsigned hi = __shfl_xor((unsigned)(mw >> 32), off, 64);
      unsigned long long o = ((unsigned long long)hi << 32) | lo;
      mw = (o < mw) ? o : mw;
    }
    if (lane == t) keep = mw;
    if (cur == mw) {                      // winner pops its front
      #pragma unroll
      for (int q = 0; q < KP1 - 1; ++q) { tv[q] = tv[q+1]; ti[q] = ti[q+1]; }
      tv[KP1-1] = INFINITY; ti[KP1-1] = -1;
      cur = skey(tv[0], ti[0]);
    }
  }
  if (lane < KP1) {
    int idx = (int)(unsigned)(keep & 0xFFFFFFFFull);
    inds[(size_t)row * KP1 + lane] = idx;
    atomicAdd(&DE[idx], 1);
  }
}

// ---------- K3: t = Dv^{-1/2} * (x @ W^T + b) ----------
// grid 512: 4 waves/block x 4 rows/wave.
__global__ void k_lin(const float* __restrict__ X, const float* __restrict__ W,
                      const float* __restrict__ bias, float* __restrict__ t) {
  int lane = threadIdx.x & 63;
  int wave = threadIdx.x >> 6;
  int rowbase = (blockIdx.x * 4 + wave) * 4;
  float wr[CH];
  {
    const float4* wp = (const float4*)(W + (size_t)lane * CH);
    #pragma unroll
    for (int k = 0; k < CH / 4; ++k) {
      float4 v = wp[k];
      wr[4*k+0] = v.x; wr[4*k+1] = v.y; wr[4*k+2] = v.z; wr[4*k+3] = v.w;
    }
  }
  float bc = bias[lane];
  #pragma unroll
  for (int r = 0; r < 4; ++r) {
    int row = __builtin_amdgcn_readfirstlane(rowbase + r);
    const float* xp = X + (size_t)row * CH;
    float d0 = 0.f, d1 = 0.f, d2 = 0.f, d3 = 0.f;
    #pragma unroll
    for (int k = 0; k < CH / 4; ++k) {
      d0 = fmaf(wr[4*k+0], xp[4*k+0], d0);
      d1 = fmaf(wr[4*k+1], xp[4*k+1], d1);
      d2 = fmaf(wr[4*k+2], xp[4*k+2], d2);
      d3 = fmaf(wr[4*k+3], xp[4*k+3], d3);
    }
    float y = (d0 + d1) + (d2 + d3) + bc;
    t[(size_t)row * CH + lane] = y * dv2_of(row);
  }
}

// ---------- K4: fused edge sums — scatter (KNN, atomics) + local patches ----------
// grid 2048+392: first 2048 blocks = scatter (4 nodes each), rest = local (4 edges each).
__global__ void k_edge(const float* __restrict__ t, const int* __restrict__ inds,
                       float* __restrict__ s_knn, float* __restrict__ s_loc) {
  int c = threadIdx.x & 63;
  int w = threadIdx.x >> 6;
  if (blockIdx.x < BNTOT / 4) {
    int u = blockIdx.x * 4 + w;
    float val = t[(size_t)u * CH + c];
    int ub = __builtin_amdgcn_readfirstlane(u);
    const int* ip = inds + (size_t)ub * KP1;
    #pragma unroll
    for (int j = 0; j < KP1; ++j) {
      int e = ip[j];
      atomicAdd(&s_knn[(size_t)e * CH + c], val);
    }
  } else {
    int e = (blockIdx.x - BNTOT / 4) * 4 + w;
    int b  = e / 196;
    int le = e - b * 196;
    int pi = le / 14;
    int pj = le - pi * 14;
    int base = b * 1024 + (pi * 2) * 32 + pj * 2;
    float acc = 0.f;
    #pragma unroll
    for (int di = 0; di < 5; ++di)
      #pragma unroll
      for (int dj = 0; dj < 5; ++dj)
        acc += t[(size_t)(base + di * 32 + dj) * CH + c];
    s_loc[(size_t)e * CH + c] = acc * (1.0f / 25.0f);
  }
}

// ---------- K5: gather + per-block BN partials (R14/R16-proven gather body) ----------
__global__ void k_gatherbn(const float* __restrict__ s_knn, const float* __restrict__ s_loc,
                           const int* __restrict__ inds, const int* __restrict__ DE,
                           float* __restrict__ z, float* __restrict__ part,
                           float* __restrict__ partsq) {
  int c = threadIdx.x & 63;
  int w = threadIdx.x >> 6;
  int u = blockIdx.x * 4 + w;
  int ub = __builtin_amdgcn_readfirstlane(u);
  const int* ip = inds + (size_t)ub * KP1;
  float acc = 0.f;
  #pragma unroll
  for (int j = 0; j < KP1; ++j) {
    int e = ip[j];
    float invde = 1.0f / (float)DE[e];
    acc += s_knn[(size_t)e * CH + c] * invde;
  }
  int node = ub & 1023, b = ub >> 10;
  int rr = node >> 5, cc = node & 31;
  int i0 = rr - 4; if (i0 < 0) i0 = 0; i0 += (i0 & 1);
  int i1 = rr; if (i1 > 26) i1 = 26;
  int j0 = cc - 4; if (j0 < 0) j0 = 0; j0 += (j0 & 1);
  int j1 = cc; if (j1 > 26) j1 = 26;
  for (int i = i0; i <= i1; i += 2)
    for (int jj = j0; jj <= j1; jj += 2) {
      int e = b * 196 + (i >> 1) * 14 + (jj >> 1);
      acc += s_loc[(size_t)e * CH + c];
    }
  float zv = acc * dv2_of(ub);
  z[(size_t)ub * CH + c] = zv;

  __shared__ float ls[4][CH], ls2[4][CH];
  ls[w][c] = zv; ls2[w][c] = zv * zv;
  __syncthreads();
  if (threadIdx.x < 64) {
    part[(size_t)blockIdx.x * CH + c]   = ls[0][c] + ls[1][c] + ls[2][c] + ls[3][c];
    partsq[(size_t)blockIdx.x * CH + c] = ls2[0][c] + ls2[1][c] + ls2[2][c] + ls2[3][c];
  }
}

// ---------- K6: parallel reduce 2048 partials -> 32 (k_bnpart-shaped, R16-proven) ----------
__global__ void k_bnfin1(const float* __restrict__ part, const float* __restrict__ partsq,
                         float* __restrict__ part2, float* __restrict__ partsq2) {
  int c = threadIdx.x & 63;
  int rq = threadIdx.x >> 6;
  int blk = blockIdx.x;
  float s = 0.f, s2 = 0.f;
  for (int k = 0; k < 16; ++k) {
    size_t r = (size_t)(blk * 64 + rq * 16 + k) * CH + c;
    s += part[r]; s2 += partsq[r];
  }
  __shared__ float ls[4][CH], ls2[4][CH];
  ls[rq][c] = s; ls2[rq][c] = s2;
  __syncthreads();
  if (rq == 0) {
    part2[(size_t)blk * CH + c]   = ls[0][c] + ls[1][c] + ls[2][c] + ls[3][c];
    partsq2[(size_t)blk * CH + c] = ls2[0][c] + ls2[1][c] + ls2[2][c] + ls2[3][c];
  }
}

// ---------- K7: BN finalize (32 partials) + apply + relu + residual (R16-proven) ----------
__global__ void k_out(const float* __restrict__ z, const float* __restrict__ X,
                      const float* __restrict__ part2, const float* __restrict__ partsq2,
                      const float* __restrict__ gamma, const float* __restrict__ beta,
                      float* __restrict__ out) {
  __shared__ float ls[4][CH], ls2[4][CH], smu[CH], srstd[CH];
  int c = threadIdx.x & 63;
  int w = threadIdx.x >> 6;
  // prologue: reduce the 32 level-2 partials (8 per wave)
  float s = 0.f, s2 = 0.f;
  #pragma unroll
  for (int b = 0; b < 8; ++b) {
    size_t r = (size_t)(w * 8 + b) * CH + c;
    s += part2[r]; s2 += partsq2[r];
  }
  ls[w][c] = s; ls2[w][c] = s2;
  __syncthreads();
  if (threadIdx.x < 64) {
    float S  = ls[0][c] + ls[1][c] + ls[2][c] + ls[3][c];
    float S2 = ls2[0][c] + ls2[1][c] + ls2[2][c] + ls2[3][c];
    float m = S * (1.0f / (float)BNTOT);
    float var = S2 * (1.0f / (float)BNTOT) - m * m;
    smu[c] = m;
    srstd[c] = 1.0f / sqrtf(var + 1e-5f);
  }
  __syncthreads();

  int u = blockIdx.x * 4 + w;
  size_t idx = (size_t)u * CH + c;
  float zn = (z[idx] - smu[c]) * srstd[c] * gamma[c] + beta[c];
  out[idx] = fmaxf(zn, 0.f) + X[idx];
}

// ---------- launch ----------
extern "C" void kernel_launch(void* const* d_in, const int* in_sizes, int n_in,
                              void* d_out, int out_size, void* d_ws, size_t ws_size,
                              hipStream_t stream) {
  const float* X     = (const float*)d_in[0];
  const float* W     = (const float*)d_in[1];
  const float* bias  = (const float*)d_in[2];
  const float* gamma = (const float*)d_in[3];
  const float* beta  = (const float*)d_in[4];
  float* out = (float*)d_out;

  // workspace layout
  float* ws = (float*)d_ws;
  float* sq      = ws;                        // 8192
  float* thr     = sq + 8192;                 // 8192
  float* t       = thr + 8192;                // 524288
  float* s_loc   = t + 524288;                // 100352
  float* z       = s_loc + 100352;            // 524288
  float* part    = z + 524288;                // 2048*64 = 131072
  float* partsq  = part + 131072;             // 131072
  float* part2   = partsq + 131072;           // 32*64 = 2048
  float* partsq2 = part2 + 2048;              // 2048
  float* thrpart = partsq2 + 2048;            // 1024*64*11 = 720896
  int*   inds    = (int*)(thrpart + 720896);  // 90112 ints
  unsigned short* Xh = (unsigned short*)(inds + 90112);   // 524288 shorts
  uint2* cand    = (uint2*)(Xh + 524288);                 // 8192*256 uint2 = 16 MB
  // zeroed region: cnt (8192 int) + DE (8192 int) + s_knn (524288 f), contiguous
  int*   cnt    = (int*)(cand + (size_t)8192 * CAP);
  int*   DE     = cnt + 8192;
  float* s_knn  = (float*)(DE + 8192);

  hipMemsetAsync(cnt, 0, (size_t)(8192 + 8192 + 524288) * 4, stream);

  k_cast    <<<2048, 256, 0, stream>>>(X, Xh, sq);
  k_thrpart <<<1024, 256, 0, stream>>>(X, sq, thrpart);
  k_thrmerge<<<128, 64, 0, stream>>>(thrpart, thr);
  k_filter  <<<4096, 256, 0, stream>>>(Xh, sq, thr, cnt, cand);
  k_rescore <<<2048, 256, 0, stream>>>(X, sq, cnt, cand, inds, DE);
  k_lin     <<<512, 256, 0, stream>>>(X, W, bias, t);
  k_edge    <<<BNTOT / 4 + NLOC / 4, 256, 0, stream>>>(t, inds, s_knn, s_loc);
  k_gatherbn<<<BNTOT / 4, 256, 0, stream>>>(s_knn, s_loc, inds, DE, z, part, partsq);
  k_bnfin1  <<<32, 256, 0, stream>>>(part, partsq, part2, partsq2);
  k_out     <<<BNTOT / 4, 256, 0, stream>>>(z, X, part2, partsq2, gamma, beta, out);

  (void)in_sizes; (void)n_in; (void)out_size; (void)ws_size;
}